// Round 8
// baseline (2210.779 us; speedup 1.0000x reference)
//
#include <hip/hip_runtime.h>
#include <math.h>

#define NN 50000
#define NP 50048      // NN padded to 64; all node arrays sized NP
#define NB 782        // NP/64
#define IN_DIM 16
#define DD 128
#define HH 256
#define NE 800000
#define NLAYERS 3
#define ET (NE + NN)

typedef unsigned short ushort_t;
typedef unsigned int uint_t;
typedef __attribute__((ext_vector_type(8))) short bf16x8;   // 8 bf16 = 4 VGPRs
typedef __attribute__((ext_vector_type(4))) float f32x4;

// tanh(x) = 1 - 2*rcp(exp2(2x*log2e)+1); ±inf exact
__device__ __forceinline__ float fast_tanh(float x) {
  float e = __builtin_amdgcn_exp2f(x * 2.88539008177793f);
  float r = __builtin_amdgcn_rcpf(e + 1.0f);
  return fmaf(-2.0f, r, 1.0f);
}

__device__ __forceinline__ float fast_sigmoid(float x) {
  float e = __builtin_amdgcn_exp2f(x * -1.44269504088896f);
  return __builtin_amdgcn_rcpf(e + 1.0f);
}

__device__ __forceinline__ ushort_t f2bf(float f) {  // RNE fp32->bf16
  uint_t u = __float_as_uint(f);
  u += 0x7FFFu + ((u >> 16) & 1u);
  return (ushort_t)(u >> 16);
}

// pack 2 fp32 -> 2 bf16 (RNE) in one dword; single v_cvt_pk_bf16_f32 on gfx950
__device__ __forceinline__ uint_t pack2bf(float lo, float hi) {
#if __has_builtin(__builtin_amdgcn_cvt_pk_bf16_f32)
  auto v = __builtin_amdgcn_cvt_pk_bf16_f32(lo, hi);
  uint_t r;
  __builtin_memcpy(&r, &v, 4);
  return r;
#else
  return (uint_t)f2bf(lo) | ((uint_t)f2bf(hi) << 16);
#endif
}

__device__ __forceinline__ float bflo(uint_t d) { return __uint_as_float(d << 16); }
__device__ __forceinline__ float bfhi(uint_t d) { return __uint_as_float(d & 0xFFFF0000u); }

// h_bf / agg-frag GLOBAL layout (B-operand frags, K=128), per 64-node group:
//   addr = g64*8192 + ((ct*4 + ks)*64 + q*16 + mr)*8 + j
// hC (fp32 h in C-fragment layout), per 64-node group:
//   addr = g64*8192 + ((row16*4 + quad)*64 + ct*16 + col)*4 + r
//   where node = g64*64 + ct*16 + col, dim = row16*16 + quad*4 + r.

// ---------------- CSR counting sort (built once, reused 3 layers) ----------------

__global__ void deg_kernel(const int* __restrict__ etgt, int* __restrict__ deg) {
  int e = blockIdx.x * blockDim.x + threadIdx.x;
  if (e >= ET) return;
  int tg = (e < NE) ? etgt[e] : (e - NE);
  atomicAdd(&deg[tg], 1);
}

__global__ __launch_bounds__(1024) void scan_kernel(const int* __restrict__ deg,
                                                    int* __restrict__ cursor,
                                                    float* __restrict__ invc) {
  __shared__ int wsum[16];
  __shared__ int carry_s;
  const int t = threadIdx.x;
  const int lane = t & 63, wid = t >> 6;
  if (t == 0) carry_s = 0;
  __syncthreads();
  for (int base = 0; base < NN; base += 1024) {
    int i = base + t;
    int d = (i < NN) ? deg[i] : 0;
    int v = d;
#pragma unroll
    for (int off = 1; off < 64; off <<= 1) {
      int u = __shfl_up(v, off);
      if (lane >= off) v += u;
    }
    if (lane == 63) wsum[wid] = v;
    __syncthreads();
    int woff = 0;
    for (int k = 0; k < wid; ++k) woff += wsum[k];
    int incl = v + woff;
    int carry = carry_s;
    __syncthreads();
    if (i < NN) {
      cursor[i] = carry + incl - d;
      invc[i] = 1.0f / (float)d;
    }
    if (t == 1023) carry_s = carry + incl;
    __syncthreads();
  }
}

__global__ void scatter_kernel(const int* __restrict__ esrc, const int* __restrict__ etgt,
                               int* __restrict__ cursor, int* __restrict__ sSrc,
                               int* __restrict__ sTgt) {
  int e = blockIdx.x * blockDim.x + threadIdx.x;
  if (e >= ET) return;
  int s, tg;
  if (e < NE) { s = esrc[e]; tg = etgt[e]; }
  else        { s = e - NE;  tg = s; }
  int pos = atomicAdd(&cursor[tg], 1);
  sSrc[pos] = s;
  sTgt[pos] = tg;
}

// ---------------------------------------------------------------------------------

__global__ void encoder_kernel(const float* __restrict__ x, const float* __restrict__ W,
                               const float* __restrict__ b, float* __restrict__ hC,
                               ushort_t* __restrict__ hbf) {
  int idx = blockIdx.x * blockDim.x + threadIdx.x;
  if (idx >= NN * DD) return;
  int n = idx >> 7, j = idx & (DD - 1);
  const float* xr = x + n * IN_DIM;
  float acc = b[j];
#pragma unroll
  for (int k = 0; k < IN_DIM; ++k) acc = fmaf(xr[k], W[k * DD + j], acc);
  float v = fast_tanh(acc);
  // hC: C-frag layout
  hC[(size_t)(n >> 6) * 8192 + (j >> 2) * 256 + (n & 63) * 4 + (j & 3)] = v;
  const int ct = (n >> 4) & 3, mr = n & 15, ks = j >> 5, q = (j >> 3) & 3, jj = j & 7;
  hbf[(size_t)(n >> 6) * 8192 + (((ct * 4 + ks) * 64) + q * 16 + mr) * 8 + jj] = f2bf(v);
}

// Pack W[K x M] (row-major) into bf16 A-frag order; blockIdx.y = layer.
__global__ void pack_kernel(const float* __restrict__ W, ushort_t* __restrict__ out,
                            int M, int kbsh, int ngrp, int srcStride, int outStride) {
  int tid = blockIdx.x * blockDim.x + threadIdx.x;
  if (tid >= ngrp * 64) return;
  const float* Ws = W + (size_t)blockIdx.y * srcStride;
  ushort_t* os = out + (size_t)blockIdx.y * outStride;
  int lane = tid & 63, g = tid >> 6;
  int ks = g & ((1 << kbsh) - 1);
  int rt = g >> kbsh;
  int m = rt * 16 + (lane & 15);
  int k0 = ks * 32 + ((lane >> 4) << 3);
  uint_t p[4];
#pragma unroll
  for (int d = 0; d < 4; ++d)
    p[d] = pack2bf(Ws[(size_t)(k0 + 2 * d) * M + m], Ws[(size_t)(k0 + 2 * d + 1) * M + m]);
  uint4 o;
  o.x = p[0]; o.y = p[1]; o.z = p[2]; o.w = p[3];
  *(uint4*)(os + (size_t)tid * 8) = o;
}

// Pt/Ps = h @ W1 (+b1 on Pt), MFMA, no LDS. 64 nodes/block, 4 waves.
__global__ __launch_bounds__(256) void proj_kernel(
    const ushort_t* __restrict__ hbf, const ushort_t* __restrict__ W1p,
    const float* __restrict__ b1, ushort_t* __restrict__ Ptb, ushort_t* __restrict__ Psb) {
  const int t = threadIdx.x, blk = blockIdx.x;
  const int w = t >> 6, l = t & 63, quad = l >> 4, col = l & 15;
  const ushort_t* hb = hbf + (size_t)blk * 8192;
#pragma unroll
  for (int half = 0; half < 2; ++half) {
    f32x4 acc[4][4];
#pragma unroll
    for (int m = 0; m < 4; ++m)
#pragma unroll
      for (int ct = 0; ct < 4; ++ct) acc[m][ct] = (f32x4){0.f, 0.f, 0.f, 0.f};
#pragma unroll
    for (int ks = 0; ks < 4; ++ks) {
      bf16x8 af[4];
#pragma unroll
      for (int m = 0; m < 4; ++m)
        af[m] = *(const bf16x8*)&W1p[((size_t)((w * 4 + m) * 8 + half * 4 + ks) * 64 + l) * 8];
#pragma unroll
      for (int ct = 0; ct < 4; ++ct) {
        bf16x8 bf = *(const bf16x8*)&hb[((ct * 4 + ks) * 64 + l) * 8];
#pragma unroll
        for (int m = 0; m < 4; ++m)
          acc[m][ct] = __builtin_amdgcn_mfma_f32_16x16x32_bf16(af[m], bf, acc[m][ct], 0, 0, 0);
      }
    }
    ushort_t* out = half ? Psb : Ptb;
#pragma unroll
    for (int m = 0; m < 4; ++m) {
      const int o0 = (w * 4 + m) * 16 + quad * 4;
      f32x4 bb = (f32x4){0.f, 0.f, 0.f, 0.f};
      if (half == 0) bb = *(const f32x4*)(b1 + o0);
#pragma unroll
      for (int ct = 0; ct < 4; ++ct) {
        const size_t node = (size_t)blk * 64 + ct * 16 + col;
        uint2 d;
        d.x = pack2bf(acc[m][ct][0] + bb[0], acc[m][ct][1] + bb[1]);
        d.y = pack2bf(acc[m][ct][2] + bb[2], acc[m][ct][3] + bb[3]);
        *(uint2*)&out[node * HH + o0] = d;
      }
    }
  }
}

// MFMA edge kernel, target-sorted edges, wave-cooperative weights.
// LDS = exactly 32 KB (msg region swizzled: off(e,m) = e*128 + ((m+4e)&127),
// banks rotate 4/edge -> 2-way = free); indices kept in registers, reduction
// walks targets via __shfl. 5 blocks/CU.
__global__ __launch_bounds__(256, 5) void edge_kernel(
    const int* __restrict__ sSrc, const int* __restrict__ sTgt,
    const ushort_t* __restrict__ Ptb, const ushort_t* __restrict__ Psb,
    const ushort_t* __restrict__ W2p, const float* __restrict__ b2,
    const ushort_t* __restrict__ W3p, const float* __restrict__ b3,
    const float* __restrict__ invc, float* __restrict__ agg) {
  __shared__ __align__(16) float vBf[64 * 128];  // 32 KB exactly; aliased bf16 frag buf
  ushort_t* vB = (ushort_t*)vBf;
  const int t = threadIdx.x;
  const int e0 = blockIdx.x * 64;
  // stage 1: bf16 gather + tanh -> vB (B-frag order). thread (el=t&63, c=t>>6)
  {
    const int el = t & 63, c = t >> 6;
    const int eg = e0 + el;
    int s = 0, tg = 0;
    if (eg < ET) { s = sSrc[eg]; tg = sTgt[eg]; }
    const uint4* pt = (const uint4*)(Ptb + (size_t)tg * HH + c * 64);
    const uint4* ps = (const uint4*)(Psb + (size_t)s * HH + c * 64);
    const int ct = el >> 4, mr = el & 15;
#pragma unroll
    for (int g = 0; g < 8; ++g) {
      uint4 av = pt[g];
      uint4 bv = ps[g];
      uint_t ad[4] = {av.x, av.y, av.z, av.w};
      uint_t bd[4] = {bv.x, bv.y, bv.z, bv.w};
      uint_t p[4];
#pragma unroll
      for (int d = 0; d < 4; ++d) {
        float flo = bflo(ad[d]) + bflo(bd[d]);
        float fhi = bfhi(ad[d]) + bfhi(bd[d]);
        p[d] = pack2bf(fast_tanh(flo), fast_tanh(fhi));
      }
      uint4 o;
      o.x = p[0]; o.y = p[1]; o.z = p[2]; o.w = p[3];
      const int ks = c * 2 + (g >> 2);
      const int quad = g & 3;
      *(uint4*)&vB[((ct * 8 + ks) * 64 + quad * 16 + mr) * 8] = o;
    }
  }
  __syncthreads();
  const int w = t >> 6, l = t & 63;
  const int quad = l >> 4, col = l & 15;
  // stage 2: u^T — wave w does A-rows rt = 4w..4w+3, all 4 edge tiles
  f32x4 acc2[4][4];
#pragma unroll
  for (int rp = 0; rp < 4; ++rp)
#pragma unroll
    for (int ct = 0; ct < 4; ++ct) acc2[rp][ct] = (f32x4){0.f, 0.f, 0.f, 0.f};
#pragma unroll
  for (int ks = 0; ks < 8; ++ks) {
    bf16x8 bfrag[4];
#pragma unroll
    for (int ct = 0; ct < 4; ++ct)
      bfrag[ct] = *(const bf16x8*)&vB[((ct * 8 + ks) * 64 + l) * 8];
#pragma unroll
    for (int rp = 0; rp < 4; ++rp) {
      bf16x8 afrag = *(const bf16x8*)&W2p[((size_t)((w * 4 + rp) * 8 + ks) * 64 + l) * 8];
#pragma unroll
      for (int ct = 0; ct < 4; ++ct)
        acc2[rp][ct] = __builtin_amdgcn_mfma_f32_16x16x32_bf16(afrag, bfrag[ct], acc2[rp][ct], 0, 0, 0);
    }
  }
  __syncthreads();
#pragma unroll
  for (int rp = 0; rp < 4; ++rp) {
    f32x4 bb = *(const f32x4*)(b2 + w * 64 + rp * 16 + quad * 4);
#pragma unroll
    for (int ct = 0; ct < 4; ++ct) {
      uint2 d;
      d.x = pack2bf(fast_tanh(acc2[rp][ct][0] + bb[0]), fast_tanh(acc2[rp][ct][1] + bb[1]));
      d.y = pack2bf(fast_tanh(acc2[rp][ct][2] + bb[2]), fast_tanh(acc2[rp][ct][3] + bb[3]));
      const int gidx = (ct * 8 + w * 2 + (rp >> 1)) * 64 + ((rp & 1) * 2 + (quad >> 1)) * 16 + col;
      *(uint2*)&vB[gidx * 8 + (quad & 1) * 4] = d;
    }
  }
  __syncthreads();
  // stage 3: msg^T — wave w does A-rows 2w..2w+1
  f32x4 acc3[2][4];
#pragma unroll
  for (int rp = 0; rp < 2; ++rp)
#pragma unroll
    for (int ct = 0; ct < 4; ++ct) acc3[rp][ct] = (f32x4){0.f, 0.f, 0.f, 0.f};
#pragma unroll
  for (int ks = 0; ks < 8; ++ks) {
    bf16x8 bfrag[4];
#pragma unroll
    for (int ct = 0; ct < 4; ++ct)
      bfrag[ct] = *(const bf16x8*)&vB[((ct * 8 + ks) * 64 + l) * 8];
#pragma unroll
    for (int rp = 0; rp < 2; ++rp) {
      bf16x8 afrag = *(const bf16x8*)&W3p[((size_t)((w * 2 + rp) * 8 + ks) * 64 + l) * 8];
#pragma unroll
      for (int ct = 0; ct < 4; ++ct)
        acc3[rp][ct] = __builtin_amdgcn_mfma_f32_16x16x32_bf16(afrag, bfrag[ct], acc3[rp][ct], 0, 0, 0);
    }
  }
  __syncthreads();
  // write msg (+b3) swizzled: off(e,m) = e*128 + ((m + 4e) & 127)
  {
#pragma unroll
    for (int rp = 0; rp < 2; ++rp) {
      const int m0 = w * 32 + rp * 16 + quad * 4;
      f32x4 b3v = *(const f32x4*)(b3 + m0);
#pragma unroll
      for (int ct = 0; ct < 4; ++ct) {
        const int e = ct * 16 + col;
        float4 o4;
        o4.x = acc3[rp][ct][0] + b3v[0];
        o4.y = acc3[rp][ct][1] + b3v[1];
        o4.z = acc3[rp][ct][2] + b3v[2];
        o4.w = acc3[rp][ct][3] + b3v[3];
        *(float4*)(vBf + e * 128 + ((m0 + 4 * e) & 127)) = o4;
      }
    }
  }
  __syncthreads();
  // segmented reduction (targets in registers, walked via shfl; 1/deg folded)
  {
    const int j = t & 127;
    const int hb = t >> 7;
    const int eg = e0 + hb * 32 + (l & 31);
    int tv = (eg < ET) ? sTgt[eg] : -1;
    int cur = __shfl(tv, 0);
    float a = 0.f;
    for (int i = 0; i < 32; ++i) {
      int tg = __shfl(tv, i);
      if (tg != cur) {
        if (cur >= 0) atomicAdd(&agg[(size_t)cur * DD + j], a * invc[cur]);
        a = 0.f;
        cur = tg;
      }
      const int e = hb * 32 + i;
      a += vBf[e * 128 + ((j + 4 * e) & 127)];
    }
    if (cur >= 0) atomicAdd(&agg[(size_t)cur * DD + j], a * invc[cur]);
  }
}

// Fused GRU: agg staged to B-frags in LDS; h fp32 lives in C-frag layout (hC)
// so each lane reads/writes its own coalesced float4 — no h LDS tile.
__global__ __launch_bounds__(256, 4) void gru_kernel(
    const float* __restrict__ agg, float* __restrict__ hC,
    const ushort_t* __restrict__ hbf_in,
    const ushort_t* __restrict__ Wihp, const ushort_t* __restrict__ Whhp,
    const float* __restrict__ bih, const float* __restrict__ bhh,
    ushort_t* __restrict__ hbf_out) {
  __shared__ __align__(16) ushort_t aggF[64 * 128];  // 16 KB, B-frag
  const int t = threadIdx.x, blk = blockIdx.x;
  const size_t nodeBase = (size_t)blk * 64;
  {
    const int row = t >> 2, c = t & 3;
    const float4* ap = (const float4*)(agg + (nodeBase + row) * DD + c * 32);
    const int ct = row >> 4, mr = row & 15;
#pragma unroll
    for (int g = 0; g < 8; ++g) {
      float4 v = ap[g];
      uint2 d;
      d.x = pack2bf(v.x, v.y);
      d.y = pack2bf(v.z, v.w);
      *(uint2*)&aggF[(((ct * 4 + c) * 64) + (g >> 1) * 16 + mr) * 8 + (g & 1) * 4] = d;
    }
  }
  __syncthreads();
  const int w = t >> 6, l = t & 63, quad = l >> 4, col = l & 15;
  const ushort_t* hbf_blk = hbf_in + nodeBase * DD;
  float* hC_blk = hC + nodeBase * DD;
  f32x4 bbr[2], bbz[2], bbin[2], bbhn[2];
#pragma unroll
  for (int m = 0; m < 2; ++m) {
    const int o = (w + 4 * m) * 16 + quad * 4;
    f32x4 i0 = *(const f32x4*)(bih + o),       h0 = *(const f32x4*)(bhh + o);
    f32x4 i1 = *(const f32x4*)(bih + o + 128), h1 = *(const f32x4*)(bhh + o + 128);
    bbr[m] = i0 + h0;
    bbz[m] = i1 + h1;
    bbin[m] = *(const f32x4*)(bih + o + 256);
    bbhn[m] = *(const f32x4*)(bhh + o + 256);
  }
  for (int ct = 0; ct < 4; ++ct) {
    f32x4 acc[8];
#pragma unroll
    for (int i = 0; i < 8; ++i) acc[i] = (f32x4){0.f, 0.f, 0.f, 0.f};
#pragma unroll
    for (int ks = 0; ks < 8; ++ks) {
      bf16x8 bfrag;
      if (ks < 4) bfrag = *(const bf16x8*)&aggF[((ct * 4 + ks) * 64 + l) * 8];
      else        bfrag = *(const bf16x8*)&hbf_blk[((ct * 4 + (ks - 4)) * 64 + l) * 8];
#pragma unroll
      for (int i = 0; i < 6; ++i) {
        const int rt = w + 4 * i;
        bf16x8 afrag = (ks < 4)
            ? *(const bf16x8*)&Wihp[((size_t)(rt * 4 + ks) * 64 + l) * 8]
            : *(const bf16x8*)&Whhp[((size_t)(rt * 4 + ks - 4) * 64 + l) * 8];
        const int tgt = (i < 4) ? i : ((ks < 4) ? i : i + 2);
        acc[tgt] = __builtin_amdgcn_mfma_f32_16x16x32_bf16(afrag, bfrag, acc[tgt], 0, 0, 0);
      }
    }
#pragma unroll
    for (int m = 0; m < 2; ++m) {
      float* hp = hC_blk + ((((w + 4 * m) * 4 + quad) * 64) + ct * 16 + col) * 4;
      f32x4 hv = *(const f32x4*)hp;
      f32x4 hnew;
#pragma unroll
      for (int r = 0; r < 4; ++r) {
        float rr = fast_sigmoid(acc[m][r] + bbr[m][r]);
        float zz = fast_sigmoid(acc[2 + m][r] + bbz[m][r]);
        float gin = acc[4 + m][r] + bbin[m][r];
        float ghn = acc[6 + m][r] + bbhn[m][r];
        float nn = fast_tanh(fmaf(rr, ghn, gin));
        hnew[r] = fmaf(zz, hv[r] - nn, nn);
      }
      *(f32x4*)hp = hnew;
      uint2 d;
      d.x = pack2bf(hnew[0], hnew[1]);
      d.y = pack2bf(hnew[2], hnew[3]);
      const int ksn = 2 * m + (w >> 1);
      const int qn = 2 * (w & 1) + (quad >> 1);
      *(uint2*)&hbf_out[nodeBase * DD + (((ct * 4 + ksn) * 64) + qn * 16 + col) * 8 + 4 * (quad & 1)] = d;
    }
  }
}

// Fused decoder (unchanged)
__global__ __launch_bounds__(256) void dec_kernel(
    const ushort_t* __restrict__ hbf, const ushort_t* __restrict__ W1p,
    const float* __restrict__ b1, const ushort_t* __restrict__ W2p,
    const float* __restrict__ b2, const float* __restrict__ w3,
    const float* __restrict__ b3, float* __restrict__ out) {
  __shared__ __align__(16) ushort_t o1F[64 * 256];  // 32 KB
  __shared__ float red[16][64];                     // 4 KB
  const int t = threadIdx.x, blk = blockIdx.x;
  const int w = t >> 6, l = t & 63, quad = l >> 4, col = l & 15;
  const ushort_t* hb = hbf + (size_t)blk * 8192;
  {
    f32x4 a1[4][4];
#pragma unroll
    for (int m = 0; m < 4; ++m)
#pragma unroll
      for (int ct = 0; ct < 4; ++ct) a1[m][ct] = (f32x4){0.f, 0.f, 0.f, 0.f};
#pragma unroll
    for (int ks = 0; ks < 4; ++ks) {
      bf16x8 af[4];
#pragma unroll
      for (int m = 0; m < 4; ++m)
        af[m] = *(const bf16x8*)&W1p[((size_t)((w * 4 + m) * 4 + ks) * 64 + l) * 8];
#pragma unroll
      for (int ct = 0; ct < 4; ++ct) {
        bf16x8 bf = *(const bf16x8*)&hb[((ct * 4 + ks) * 64 + l) * 8];
#pragma unroll
        for (int m = 0; m < 4; ++m)
          a1[m][ct] = __builtin_amdgcn_mfma_f32_16x16x32_bf16(af[m], bf, a1[m][ct], 0, 0, 0);
      }
    }
#pragma unroll
    for (int m = 0; m < 4; ++m) {
      const int o0 = (w * 4 + m) * 16 + quad * 4;
      f32x4 bb = *(const f32x4*)(b1 + o0);
      const int ks1 = 2 * w + (m >> 1);
      const int q1 = 2 * (m & 1) + (quad >> 1);
#pragma unroll
      for (int ct = 0; ct < 4; ++ct) {
        uint2 d;
        d.x = pack2bf(fast_tanh(a1[m][ct][0] + bb[0]), fast_tanh(a1[m][ct][1] + bb[1]));
        d.y = pack2bf(fast_tanh(a1[m][ct][2] + bb[2]), fast_tanh(a1[m][ct][3] + bb[3]));
        *(uint2*)&o1F[((ct * 8 + ks1) * 64 + q1 * 16 + col) * 8 + 4 * (quad & 1)] = d;
      }
    }
  }
  __syncthreads();
  {
    f32x4 a2[4][4];
#pragma unroll
    for (int m = 0; m < 4; ++m)
#pragma unroll
      for (int ct = 0; ct < 4; ++ct) a2[m][ct] = (f32x4){0.f, 0.f, 0.f, 0.f};
#pragma unroll
    for (int ks = 0; ks < 8; ++ks) {
      bf16x8 af[4];
#pragma unroll
      for (int m = 0; m < 4; ++m)
        af[m] = *(const bf16x8*)&W2p[((size_t)((w * 4 + m) * 8 + ks) * 64 + l) * 8];
#pragma unroll
      for (int ct = 0; ct < 4; ++ct) {
        bf16x8 bf = *(const bf16x8*)&o1F[((ct * 8 + ks) * 64 + l) * 8];
#pragma unroll
        for (int m = 0; m < 4; ++m)
          a2[m][ct] = __builtin_amdgcn_mfma_f32_16x16x32_bf16(af[m], bf, a2[m][ct], 0, 0, 0);
      }
    }
    float partial[4] = {0.f, 0.f, 0.f, 0.f};
#pragma unroll
    for (int m = 0; m < 4; ++m) {
      const int o0 = (w * 4 + m) * 16 + quad * 4;
      f32x4 b2v = *(const f32x4*)(b2 + o0);
      f32x4 w3v = *(const f32x4*)(w3 + o0);
#pragma unroll
      for (int ct = 0; ct < 4; ++ct)
#pragma unroll
        for (int r = 0; r < 4; ++r)
          partial[ct] += fast_tanh(a2[m][ct][r] + b2v[r]) * w3v[r];
    }
#pragma unroll
    for (int ct = 0; ct < 4; ++ct) red[w * 4 + quad][ct * 16 + col] = partial[ct];
  }
  __syncthreads();
  if (t < 64) {
    float s = b3[0];
#pragma unroll
    for (int k = 0; k < 16; ++k) s += red[k][t];
    size_t node = (size_t)blk * 64 + t;
    if (node < NN) out[node] = s;
  }
}

extern "C" void kernel_launch(void* const* d_in, const int* in_sizes, int n_in,
                              void* d_out, int out_size, void* d_ws, size_t ws_size,
                              hipStream_t stream) {
  const float* x      = (const float*)d_in[0];
  const int*   ei     = (const int*)d_in[1];
  const float* enc_W  = (const float*)d_in[2];
  const float* enc_b  = (const float*)d_in[3];
  const float* msg_W1 = (const float*)d_in[4];
  const float* msg_b1 = (const float*)d_in[5];
  const float* msg_W2 = (const float*)d_in[6];
  const float* msg_b2 = (const float*)d_in[7];
  const float* msg_W3 = (const float*)d_in[8];
  const float* msg_b3 = (const float*)d_in[9];
  const float* gWih   = (const float*)d_in[10];
  const float* gWhh   = (const float*)d_in[11];
  const float* gbih   = (const float*)d_in[12];
  const float* gbhh   = (const float*)d_in[13];
  const float* dW1    = (const float*)d_in[14];
  const float* db1    = (const float*)d_in[15];
  const float* dW2    = (const float*)d_in[16];
  const float* db2    = (const float*)d_in[17];
  const float* dW3    = (const float*)d_in[18];
  const float* db3    = (const float*)d_in[19];
  float* out = (float*)d_out;

  float* ws = (float*)d_ws;
  float* invc = ws;                                    // NP
  float* hC   = ws + NP;                               // NP*128 fp32 (C-frag layout)
  float* agg  = hC + (size_t)NP * DD;                  // NP*128 fp32
  ushort_t* hbfA = (ushort_t*)(agg + (size_t)NP * DD); // NP*128 ush
  ushort_t* hbfB = hbfA + (size_t)NP * DD;             // NP*128 ush
  ushort_t* Ptb  = hbfB + (size_t)NP * DD;             // NP*256 ush
  ushort_t* Psb  = Ptb + (size_t)NP * HH;              // NP*256 ush
  ushort_t* W2pk = Psb + (size_t)NP * HH;              // 3*65536
  ushort_t* W3pk = W2pk + 3 * 65536;                   // 3*32768
  ushort_t* W1pk = W3pk + 3 * 32768;                   // 3*65536
  ushort_t* Wihpk = W1pk + 3 * 65536;                  // 3*49152
  ushort_t* Whhpk = Wihpk + 3 * 49152;                 // 3*49152
  ushort_t* dW1pk = Whhpk + 3 * 49152;                 // 32768
  ushort_t* dW2pk = dW1pk + 32768;                     // 65536
  int* deg    = (int*)(dW2pk + 65536);                 // NP
  int* cursor = deg + NP;                              // NP
  int* sSrc   = cursor + NP;                           // ET
  int* sTgt   = sSrc + ET;                             // ET

  const int* esrc = ei;
  const int* etgt = ei + NE;

  // edge sort (once)
  hipMemsetAsync(deg, 0, NN * sizeof(int), stream);
  deg_kernel<<<(ET + 255) / 256, 256, 0, stream>>>(etgt, deg);
  scan_kernel<<<1, 1024, 0, stream>>>(deg, cursor, invc);
  scatter_kernel<<<(ET + 255) / 256, 256, 0, stream>>>(esrc, etgt, cursor, sSrc, sTgt);

  encoder_kernel<<<(NN * DD + 255) / 256, 256, 0, stream>>>(x, enc_W, enc_b, hC, hbfA);

  // weight packs (once, all layers)
  pack_kernel<<<dim3(32, 3), 256, 0, stream>>>(msg_W2, W2pk, 256, 3, 128, 65536, 65536);
  pack_kernel<<<dim3(16, 3), 256, 0, stream>>>(msg_W3, W3pk, 128, 3, 64, 32768, 32768);
  pack_kernel<<<dim3(32, 3), 256, 0, stream>>>(msg_W1, W1pk, 256, 3, 128, 65536, 65536);
  pack_kernel<<<dim3(24, 3), 256, 0, stream>>>(gWih, Wihpk, 384, 2, 96, 49152, 49152);
  pack_kernel<<<dim3(24, 3), 256, 0, stream>>>(gWhh, Whhpk, 384, 2, 96, 49152, 49152);
  pack_kernel<<<dim3(16, 1), 256, 0, stream>>>(dW1, dW1pk, 256, 2, 64, 0, 0);
  pack_kernel<<<dim3(32, 1), 256, 0, stream>>>(dW2, dW2pk, 256, 3, 128, 0, 0);

  for (int l = 0; l < NLAYERS; ++l) {
    const ushort_t* hin = (l & 1) ? hbfB : hbfA;
    ushort_t* hout = (l & 1) ? hbfA : hbfB;
    proj_kernel<<<NB, 256, 0, stream>>>(hin, W1pk + (size_t)l * 65536, msg_b1 + l * HH, Ptb, Psb);
    hipMemsetAsync(agg, 0, (size_t)NP * DD * sizeof(float), stream);
    edge_kernel<<<(ET + 63) / 64, 256, 0, stream>>>(
        sSrc, sTgt, Ptb, Psb, W2pk + (size_t)l * 65536, msg_b2 + (size_t)l * HH,
        W3pk + (size_t)l * 32768, msg_b3 + (size_t)l * DD, invc, agg);
    gru_kernel<<<NB, 256, 0, stream>>>(
        agg, hC, hin, Wihpk + (size_t)l * 49152, Whhpk + (size_t)l * 49152,
        gbih + (size_t)l * 3 * DD, gbhh + (size_t)l * 3 * DD, hout);
  }
  dec_kernel<<<NB, 256, 0, stream>>>(hbfB, dW1pk, db1, dW2pk, db2, dW3, db3, out);
}

// Round 9
// 1414.105 us; speedup vs baseline: 1.5634x; 1.5634x over previous
//
#include <hip/hip_runtime.h>
#include <math.h>

#define NN 50000
#define NP 50048      // NN padded to 64; all node arrays sized NP
#define NB 782        // NP/64
#define IN_DIM 16
#define DD 128
#define HH 256
#define NE 800000
#define NLAYERS 3
#define ET (NE + NN)
#define EBLK 13282            // ceil(ET/64)
#define ESW 1661              // ceil(EBLK/8) for XCD swizzle
#define EGRID (ESW * 8)       // launched blocks (tail guarded)

typedef unsigned short ushort_t;
typedef unsigned int uint_t;
typedef __attribute__((ext_vector_type(8))) short bf16x8;   // 8 bf16 = 4 VGPRs
typedef __attribute__((ext_vector_type(4))) float f32x4;

// tanh(x) = 1 - 2*rcp(exp2(2x*log2e)+1); ±inf exact
__device__ __forceinline__ float fast_tanh(float x) {
  float e = __builtin_amdgcn_exp2f(x * 2.88539008177793f);
  float r = __builtin_amdgcn_rcpf(e + 1.0f);
  return fmaf(-2.0f, r, 1.0f);
}

__device__ __forceinline__ float fast_sigmoid(float x) {
  float e = __builtin_amdgcn_exp2f(x * -1.44269504088896f);
  return __builtin_amdgcn_rcpf(e + 1.0f);
}

__device__ __forceinline__ ushort_t f2bf(float f) {  // RNE fp32->bf16
  uint_t u = __float_as_uint(f);
  u += 0x7FFFu + ((u >> 16) & 1u);
  return (ushort_t)(u >> 16);
}

// pack 2 fp32 -> 2 bf16 (RNE) in one dword; single v_cvt_pk_bf16_f32 on gfx950
__device__ __forceinline__ uint_t pack2bf(float lo, float hi) {
#if __has_builtin(__builtin_amdgcn_cvt_pk_bf16_f32)
  auto v = __builtin_amdgcn_cvt_pk_bf16_f32(lo, hi);
  uint_t r;
  __builtin_memcpy(&r, &v, 4);
  return r;
#else
  return (uint_t)f2bf(lo) | ((uint_t)f2bf(hi) << 16);
#endif
}

__device__ __forceinline__ float bflo(uint_t d) { return __uint_as_float(d << 16); }
__device__ __forceinline__ float bfhi(uint_t d) { return __uint_as_float(d & 0xFFFF0000u); }

// h_bf / agg-frag GLOBAL layout (B-operand frags, K=128), per 64-node group:
//   addr = g64*8192 + ((ct*4 + ks)*64 + q*16 + mr)*8 + j

// ---------------- CSR counting sort (built once, reused 3 layers) ----------------

__global__ void deg_kernel(const int* __restrict__ etgt, int* __restrict__ deg) {
  int e = blockIdx.x * blockDim.x + threadIdx.x;
  if (e >= ET) return;
  int tg = (e < NE) ? etgt[e] : (e - NE);
  atomicAdd(&deg[tg], 1);
}

__global__ __launch_bounds__(1024) void scan_kernel(const int* __restrict__ deg,
                                                    int* __restrict__ cursor,
                                                    float* __restrict__ invc) {
  __shared__ int wsum[16];
  __shared__ int carry_s;
  const int t = threadIdx.x;
  const int lane = t & 63, wid = t >> 6;
  if (t == 0) carry_s = 0;
  __syncthreads();
  for (int base = 0; base < NN; base += 1024) {
    int i = base + t;
    int d = (i < NN) ? deg[i] : 0;
    int v = d;
#pragma unroll
    for (int off = 1; off < 64; off <<= 1) {
      int u = __shfl_up(v, off);
      if (lane >= off) v += u;
    }
    if (lane == 63) wsum[wid] = v;
    __syncthreads();
    int woff = 0;
    for (int k = 0; k < wid; ++k) woff += wsum[k];
    int incl = v + woff;
    int carry = carry_s;
    __syncthreads();
    if (i < NN) {
      cursor[i] = carry + incl - d;
      invc[i] = 1.0f / (float)d;
    }
    if (t == 1023) carry_s = carry + incl;
    __syncthreads();
  }
}

__global__ void scatter_kernel(const int* __restrict__ esrc, const int* __restrict__ etgt,
                               int* __restrict__ cursor, int* __restrict__ sSrc,
                               int* __restrict__ sTgt) {
  int e = blockIdx.x * blockDim.x + threadIdx.x;
  if (e >= ET) return;
  int s, tg;
  if (e < NE) { s = esrc[e]; tg = etgt[e]; }
  else        { s = e - NE;  tg = s; }
  int pos = atomicAdd(&cursor[tg], 1);
  sSrc[pos] = s;
  sTgt[pos] = tg;
}

// ---------------------------------------------------------------------------------

__global__ void encoder_kernel(const float* __restrict__ x, const float* __restrict__ W,
                               const float* __restrict__ b, float* __restrict__ h,
                               ushort_t* __restrict__ hbf) {
  int idx = blockIdx.x * blockDim.x + threadIdx.x;
  if (idx >= NN * DD) return;
  int n = idx >> 7, j = idx & (DD - 1);
  const float* xr = x + n * IN_DIM;
  float acc = b[j];
#pragma unroll
  for (int k = 0; k < IN_DIM; ++k) acc = fmaf(xr[k], W[k * DD + j], acc);
  float v = fast_tanh(acc);
  h[idx] = v;
  const int ct = (n >> 4) & 3, mr = n & 15, ks = j >> 5, q = (j >> 3) & 3, jj = j & 7;
  hbf[(size_t)(n >> 6) * 8192 + (((ct * 4 + ks) * 64) + q * 16 + mr) * 8 + jj] = f2bf(v);
}

// Pack W[K x M] (row-major) into bf16 A-frag order; blockIdx.y = layer.
__global__ void pack_kernel(const float* __restrict__ W, ushort_t* __restrict__ out,
                            int M, int kbsh, int ngrp, int srcStride, int outStride) {
  int tid = blockIdx.x * blockDim.x + threadIdx.x;
  if (tid >= ngrp * 64) return;
  const float* Ws = W + (size_t)blockIdx.y * srcStride;
  ushort_t* os = out + (size_t)blockIdx.y * outStride;
  int lane = tid & 63, g = tid >> 6;
  int ks = g & ((1 << kbsh) - 1);
  int rt = g >> kbsh;
  int m = rt * 16 + (lane & 15);
  int k0 = ks * 32 + ((lane >> 4) << 3);
  uint_t p[4];
#pragma unroll
  for (int d = 0; d < 4; ++d)
    p[d] = pack2bf(Ws[(size_t)(k0 + 2 * d) * M + m], Ws[(size_t)(k0 + 2 * d + 1) * M + m]);
  uint4 o;
  o.x = p[0]; o.y = p[1]; o.z = p[2]; o.w = p[3];
  *(uint4*)(os + (size_t)tid * 8) = o;
}

// Pt/Ps = h @ W1 (+b1 on Pt), MFMA, no LDS. 64 nodes/block, 4 waves.
__global__ __launch_bounds__(256) void proj_kernel(
    const ushort_t* __restrict__ hbf, const ushort_t* __restrict__ W1p,
    const float* __restrict__ b1, ushort_t* __restrict__ Ptb, ushort_t* __restrict__ Psb) {
  const int t = threadIdx.x, blk = blockIdx.x;
  const int w = t >> 6, l = t & 63, quad = l >> 4, col = l & 15;
  const ushort_t* hb = hbf + (size_t)blk * 8192;
#pragma unroll
  for (int half = 0; half < 2; ++half) {
    f32x4 acc[4][4];
#pragma unroll
    for (int m = 0; m < 4; ++m)
#pragma unroll
      for (int ct = 0; ct < 4; ++ct) acc[m][ct] = (f32x4){0.f, 0.f, 0.f, 0.f};
#pragma unroll
    for (int ks = 0; ks < 4; ++ks) {
      bf16x8 af[4];
#pragma unroll
      for (int m = 0; m < 4; ++m)
        af[m] = *(const bf16x8*)&W1p[((size_t)((w * 4 + m) * 8 + half * 4 + ks) * 64 + l) * 8];
#pragma unroll
      for (int ct = 0; ct < 4; ++ct) {
        bf16x8 bf = *(const bf16x8*)&hb[((ct * 4 + ks) * 64 + l) * 8];
#pragma unroll
        for (int m = 0; m < 4; ++m)
          acc[m][ct] = __builtin_amdgcn_mfma_f32_16x16x32_bf16(af[m], bf, acc[m][ct], 0, 0, 0);
      }
    }
    ushort_t* out = half ? Psb : Ptb;
#pragma unroll
    for (int m = 0; m < 4; ++m) {
      const int o0 = (w * 4 + m) * 16 + quad * 4;
      f32x4 bb = (f32x4){0.f, 0.f, 0.f, 0.f};
      if (half == 0) bb = *(const f32x4*)(b1 + o0);
#pragma unroll
      for (int ct = 0; ct < 4; ++ct) {
        const size_t node = (size_t)blk * 64 + ct * 16 + col;
        uint2 d;
        d.x = pack2bf(acc[m][ct][0] + bb[0], acc[m][ct][1] + bb[1]);
        d.y = pack2bf(acc[m][ct][2] + bb[2], acc[m][ct][3] + bb[3]);
        *(uint2*)&out[node * HH + o0] = d;
      }
    }
  }
}

// MFMA edge kernel, target-sorted edges, wave-cooperative weights, 4 blocks/CU
// (R7 config — 5/CU thrashes per-XCD L2: R8 showed WRITE 64->586 MB).
// XCD-aware swizzle: dispatch is round-robin over 8 XCDs, so bid =
// (blockIdx%8)*ESW + blockIdx/8 gives each XCD a CONTIGUOUS sorted-target range
// -> its ~3.2 MB agg slice + shared Pt rows stay resident in that XCD's 4 MB L2.
__global__ __launch_bounds__(256, 4) void edge_kernel(
    const int* __restrict__ sSrc, const int* __restrict__ sTgt,
    const ushort_t* __restrict__ Ptb, const ushort_t* __restrict__ Psb,
    const ushort_t* __restrict__ W2p, const float* __restrict__ b2,
    const ushort_t* __restrict__ W3p, const float* __restrict__ b3,
    const float* __restrict__ invc, float* __restrict__ agg) {
  __shared__ __align__(16) float vBf[64 * 132];
  __shared__ int sIdx[64];
  __shared__ int tIdx[64];
  ushort_t* vB = (ushort_t*)vBf;
  const int bid = (blockIdx.x & 7) * ESW + (blockIdx.x >> 3);
  if (bid >= EBLK) return;
  const int t = threadIdx.x;
  const int e0 = bid * 64;
  if (t < 64) {
    int e = e0 + t;
    int s = 0, tg = -1;
    if (e < ET) { s = sSrc[e]; tg = sTgt[e]; }
    sIdx[t] = s;
    tIdx[t] = tg;
  }
  __syncthreads();
  // stage 1: bf16 gather + tanh -> vB (B-frag order)
  {
    const int el = t & 63, c = t >> 6;
    int tg = tIdx[el]; if (tg < 0) tg = 0;
    const int s = sIdx[el];
    const uint4* pt = (const uint4*)(Ptb + (size_t)tg * HH + c * 64);
    const uint4* ps = (const uint4*)(Psb + (size_t)s * HH + c * 64);
    const int ct = el >> 4, mr = el & 15;
#pragma unroll
    for (int g = 0; g < 8; ++g) {
      uint4 av = pt[g];
      uint4 bv = ps[g];
      uint_t ad[4] = {av.x, av.y, av.z, av.w};
      uint_t bd[4] = {bv.x, bv.y, bv.z, bv.w};
      uint_t p[4];
#pragma unroll
      for (int d = 0; d < 4; ++d) {
        float flo = bflo(ad[d]) + bflo(bd[d]);
        float fhi = bfhi(ad[d]) + bfhi(bd[d]);
        p[d] = pack2bf(fast_tanh(flo), fast_tanh(fhi));
      }
      uint4 o;
      o.x = p[0]; o.y = p[1]; o.z = p[2]; o.w = p[3];
      const int ks = c * 2 + (g >> 2);
      const int quad = g & 3;
      *(uint4*)&vB[((ct * 8 + ks) * 64 + quad * 16 + mr) * 8] = o;
    }
  }
  __syncthreads();
  const int w = t >> 6, l = t & 63;
  const int quad = l >> 4, col = l & 15;
  // stage 2: u^T — wave w does A-rows rt = 4w..4w+3, all 4 edge tiles
  f32x4 acc2[4][4];
#pragma unroll
  for (int rp = 0; rp < 4; ++rp)
#pragma unroll
    for (int ct = 0; ct < 4; ++ct) acc2[rp][ct] = (f32x4){0.f, 0.f, 0.f, 0.f};
#pragma unroll
  for (int ks = 0; ks < 8; ++ks) {
    bf16x8 bfrag[4];
#pragma unroll
    for (int ct = 0; ct < 4; ++ct)
      bfrag[ct] = *(const bf16x8*)&vB[((ct * 8 + ks) * 64 + l) * 8];
#pragma unroll
    for (int rp = 0; rp < 4; ++rp) {
      bf16x8 afrag = *(const bf16x8*)&W2p[((size_t)((w * 4 + rp) * 8 + ks) * 64 + l) * 8];
#pragma unroll
      for (int ct = 0; ct < 4; ++ct)
        acc2[rp][ct] = __builtin_amdgcn_mfma_f32_16x16x32_bf16(afrag, bfrag[ct], acc2[rp][ct], 0, 0, 0);
    }
  }
  __syncthreads();
#pragma unroll
  for (int rp = 0; rp < 4; ++rp) {
    f32x4 bb = *(const f32x4*)(b2 + w * 64 + rp * 16 + quad * 4);
#pragma unroll
    for (int ct = 0; ct < 4; ++ct) {
      uint2 d;
      d.x = pack2bf(fast_tanh(acc2[rp][ct][0] + bb[0]), fast_tanh(acc2[rp][ct][1] + bb[1]));
      d.y = pack2bf(fast_tanh(acc2[rp][ct][2] + bb[2]), fast_tanh(acc2[rp][ct][3] + bb[3]));
      const int gidx = (ct * 8 + w * 2 + (rp >> 1)) * 64 + ((rp & 1) * 2 + (quad >> 1)) * 16 + col;
      *(uint2*)&vB[gidx * 8 + (quad & 1) * 4] = d;
    }
  }
  __syncthreads();
  // stage 3: msg^T — wave w does A-rows 2w..2w+1
  f32x4 acc3[2][4];
#pragma unroll
  for (int rp = 0; rp < 2; ++rp)
#pragma unroll
    for (int ct = 0; ct < 4; ++ct) acc3[rp][ct] = (f32x4){0.f, 0.f, 0.f, 0.f};
#pragma unroll
  for (int ks = 0; ks < 8; ++ks) {
    bf16x8 bfrag[4];
#pragma unroll
    for (int ct = 0; ct < 4; ++ct)
      bfrag[ct] = *(const bf16x8*)&vB[((ct * 8 + ks) * 64 + l) * 8];
#pragma unroll
    for (int rp = 0; rp < 2; ++rp) {
      bf16x8 afrag = *(const bf16x8*)&W3p[((size_t)((w * 2 + rp) * 8 + ks) * 64 + l) * 8];
#pragma unroll
      for (int ct = 0; ct < 4; ++ct)
        acc3[rp][ct] = __builtin_amdgcn_mfma_f32_16x16x32_bf16(afrag, bfrag[ct], acc3[rp][ct], 0, 0, 0);
    }
  }
  __syncthreads();
  {
#pragma unroll
    for (int rp = 0; rp < 2; ++rp) {
      const int m0 = w * 32 + rp * 16 + quad * 4;
      f32x4 b3v = *(const f32x4*)(b3 + m0);
#pragma unroll
      for (int ct = 0; ct < 4; ++ct) {
        float4 o4;
        o4.x = acc3[rp][ct][0] + b3v[0];
        o4.y = acc3[rp][ct][1] + b3v[1];
        o4.z = acc3[rp][ct][2] + b3v[2];
        o4.w = acc3[rp][ct][3] + b3v[3];
        *(float4*)(vBf + (ct * 16 + col) * 132 + m0) = o4;
      }
    }
  }
  __syncthreads();
  // segmented reduction with folded 1/deg
  {
    const int j = t & 127;
    const int hb = t >> 7;
    const float* colp = vBf + j;
    int cur = tIdx[hb * 32];
    float a = 0.f;
    for (int e = hb * 32; e < hb * 32 + 32; ++e) {
      int tg = tIdx[e];
      if (tg != cur) {
        if (cur >= 0) atomicAdd(&agg[(size_t)cur * DD + j], a * invc[cur]);
        a = 0.f;
        cur = tg;
      }
      a += colp[e * 132];
    }
    if (cur >= 0) atomicAdd(&agg[(size_t)cur * DD + j], a * invc[cur]);
  }
}

// Fused GRU (R7 version: agg->frags + h fp32 tile in LDS)
__global__ __launch_bounds__(256, 2) void gru_kernel(
    const float* __restrict__ agg, const float* __restrict__ hg,
    const ushort_t* __restrict__ hbf_in,
    const ushort_t* __restrict__ Wihp, const ushort_t* __restrict__ Whhp,
    const float* __restrict__ bih, const float* __restrict__ bhh,
    float* __restrict__ hg_out, ushort_t* __restrict__ hbf_out) {
  __shared__ __align__(16) ushort_t aggF[64 * 128];  // 16 KB, B-frag
  __shared__ __align__(16) float hT[64 * 132];       // 33.8 KB
  const int t = threadIdx.x, blk = blockIdx.x;
  const size_t nodeBase = (size_t)blk * 64;
  {
    const int row = t >> 2, c = t & 3;
    const float4* ap = (const float4*)(agg + (nodeBase + row) * DD + c * 32);
    const int ct = row >> 4, mr = row & 15;
#pragma unroll
    for (int g = 0; g < 8; ++g) {
      float4 v = ap[g];
      uint2 d;
      d.x = pack2bf(v.x, v.y);
      d.y = pack2bf(v.z, v.w);
      *(uint2*)&aggF[(((ct * 4 + c) * 64) + (g >> 1) * 16 + mr) * 8 + (g & 1) * 4] = d;
    }
    const float4* hp = (const float4*)(hg + (nodeBase + row) * DD + c * 32);
    float* hrow = hT + row * 132 + c * 32;
#pragma unroll
    for (int g = 0; g < 8; ++g) *(float4*)(hrow + g * 4) = hp[g];
  }
  __syncthreads();
  const int w = t >> 6, l = t & 63, quad = l >> 4, col = l & 15;
  const ushort_t* hbf_blk = hbf_in + nodeBase * DD;
  f32x4 bbr[2], bbz[2], bbin[2], bbhn[2];
#pragma unroll
  for (int m = 0; m < 2; ++m) {
    const int o = (w + 4 * m) * 16 + quad * 4;
    f32x4 i0 = *(const f32x4*)(bih + o),       h0 = *(const f32x4*)(bhh + o);
    f32x4 i1 = *(const f32x4*)(bih + o + 128), h1 = *(const f32x4*)(bhh + o + 128);
    bbr[m] = i0 + h0;
    bbz[m] = i1 + h1;
    bbin[m] = *(const f32x4*)(bih + o + 256);
    bbhn[m] = *(const f32x4*)(bhh + o + 256);
  }
  for (int ct = 0; ct < 4; ++ct) {
    f32x4 acc[8];
#pragma unroll
    for (int i = 0; i < 8; ++i) acc[i] = (f32x4){0.f, 0.f, 0.f, 0.f};
#pragma unroll
    for (int ks = 0; ks < 8; ++ks) {
      bf16x8 bfrag;
      if (ks < 4) bfrag = *(const bf16x8*)&aggF[((ct * 4 + ks) * 64 + l) * 8];
      else        bfrag = *(const bf16x8*)&hbf_blk[((ct * 4 + (ks - 4)) * 64 + l) * 8];
#pragma unroll
      for (int i = 0; i < 6; ++i) {
        const int rt = w + 4 * i;
        bf16x8 afrag = (ks < 4)
            ? *(const bf16x8*)&Wihp[((size_t)(rt * 4 + ks) * 64 + l) * 8]
            : *(const bf16x8*)&Whhp[((size_t)(rt * 4 + ks - 4) * 64 + l) * 8];
        const int tgt = (i < 4) ? i : ((ks < 4) ? i : i + 2);
        acc[tgt] = __builtin_amdgcn_mfma_f32_16x16x32_bf16(afrag, bfrag, acc[tgt], 0, 0, 0);
      }
    }
#pragma unroll
    for (int m = 0; m < 2; ++m) {
      const int or0 = (w + 4 * m) * 16 + quad * 4;
      float* hrow = hT + (ct * 16 + col) * 132 + or0;
      f32x4 hv = *(const f32x4*)hrow;
      f32x4 hnew;
#pragma unroll
      for (int r = 0; r < 4; ++r) {
        float rr = fast_sigmoid(acc[m][r] + bbr[m][r]);
        float zz = fast_sigmoid(acc[2 + m][r] + bbz[m][r]);
        float gin = acc[4 + m][r] + bbin[m][r];
        float ghn = acc[6 + m][r] + bbhn[m][r];
        float nn = fast_tanh(fmaf(rr, ghn, gin));
        hnew[r] = fmaf(zz, hv[r] - nn, nn);
      }
      *(f32x4*)hrow = hnew;
      uint2 d;
      d.x = pack2bf(hnew[0], hnew[1]);
      d.y = pack2bf(hnew[2], hnew[3]);
      const int ksn = 2 * m + (w >> 1);
      const int qn = 2 * (w & 1) + (quad >> 1);
      *(uint2*)&hbf_out[nodeBase * DD + (((ct * 4 + ksn) * 64) + qn * 16 + col) * 8 + 4 * (quad & 1)] = d;
    }
  }
  __syncthreads();
  {
    const int row = t >> 2, c = t & 3;
    float* dst = hg_out + (nodeBase + row) * DD + c * 32;
    const float* src = hT + row * 132 + c * 32;
#pragma unroll
    for (int g = 0; g < 8; ++g) *(float4*)(dst + g * 4) = *(const float4*)(src + g * 4);
  }
}

// Fused decoder
__global__ __launch_bounds__(256) void dec_kernel(
    const ushort_t* __restrict__ hbf, const ushort_t* __restrict__ W1p,
    const float* __restrict__ b1, const ushort_t* __restrict__ W2p,
    const float* __restrict__ b2, const float* __restrict__ w3,
    const float* __restrict__ b3, float* __restrict__ out) {
  __shared__ __align__(16) ushort_t o1F[64 * 256];  // 32 KB
  __shared__ float red[16][64];                     // 4 KB
  const int t = threadIdx.x, blk = blockIdx.x;
  const int w = t >> 6, l = t & 63, quad = l >> 4, col = l & 15;
  const ushort_t* hb = hbf + (size_t)blk * 8192;
  {
    f32x4 a1[4][4];
#pragma unroll
    for (int m = 0; m < 4; ++m)
#pragma unroll
      for (int ct = 0; ct < 4; ++ct) a1[m][ct] = (f32x4){0.f, 0.f, 0.f, 0.f};
#pragma unroll
    for (int ks = 0; ks < 4; ++ks) {
      bf16x8 af[4];
#pragma unroll
      for (int m = 0; m < 4; ++m)
        af[m] = *(const bf16x8*)&W1p[((size_t)((w * 4 + m) * 4 + ks) * 64 + l) * 8];
#pragma unroll
      for (int ct = 0; ct < 4; ++ct) {
        bf16x8 bf = *(const bf16x8*)&hb[((ct * 4 + ks) * 64 + l) * 8];
#pragma unroll
        for (int m = 0; m < 4; ++m)
          a1[m][ct] = __builtin_amdgcn_mfma_f32_16x16x32_bf16(af[m], bf, a1[m][ct], 0, 0, 0);
      }
    }
#pragma unroll
    for (int m = 0; m < 4; ++m) {
      const int o0 = (w * 4 + m) * 16 + quad * 4;
      f32x4 bb = *(const f32x4*)(b1 + o0);
      const int ks1 = 2 * w + (m >> 1);
      const int q1 = 2 * (m & 1) + (quad >> 1);
#pragma unroll
      for (int ct = 0; ct < 4; ++ct) {
        uint2 d;
        d.x = pack2bf(fast_tanh(a1[m][ct][0] + bb[0]), fast_tanh(a1[m][ct][1] + bb[1]));
        d.y = pack2bf(fast_tanh(a1[m][ct][2] + bb[2]), fast_tanh(a1[m][ct][3] + bb[3]));
        *(uint2*)&o1F[((ct * 8 + ks1) * 64 + q1 * 16 + col) * 8 + 4 * (quad & 1)] = d;
      }
    }
  }
  __syncthreads();
  {
    f32x4 a2[4][4];
#pragma unroll
    for (int m = 0; m < 4; ++m)
#pragma unroll
      for (int ct = 0; ct < 4; ++ct) a2[m][ct] = (f32x4){0.f, 0.f, 0.f, 0.f};
#pragma unroll
    for (int ks = 0; ks < 8; ++ks) {
      bf16x8 af[4];
#pragma unroll
      for (int m = 0; m < 4; ++m)
        af[m] = *(const bf16x8*)&W2p[((size_t)((w * 4 + m) * 8 + ks) * 64 + l) * 8];
#pragma unroll
      for (int ct = 0; ct < 4; ++ct) {
        bf16x8 bf = *(const bf16x8*)&o1F[((ct * 8 + ks) * 64 + l) * 8];
#pragma unroll
        for (int m = 0; m < 4; ++m)
          a2[m][ct] = __builtin_amdgcn_mfma_f32_16x16x32_bf16(af[m], bf, a2[m][ct], 0, 0, 0);
      }
    }
    float partial[4] = {0.f, 0.f, 0.f, 0.f};
#pragma unroll
    for (int m = 0; m < 4; ++m) {
      const int o0 = (w * 4 + m) * 16 + quad * 4;
      f32x4 b2v = *(const f32x4*)(b2 + o0);
      f32x4 w3v = *(const f32x4*)(w3 + o0);
#pragma unroll
      for (int ct = 0; ct < 4; ++ct)
#pragma unroll
        for (int r = 0; r < 4; ++r)
          partial[ct] += fast_tanh(a2[m][ct][r] + b2v[r]) * w3v[r];
    }
#pragma unroll
    for (int ct = 0; ct < 4; ++ct) red[w * 4 + quad][ct * 16 + col] = partial[ct];
  }
  __syncthreads();
  if (t < 64) {
    float s = b3[0];
#pragma unroll
    for (int k = 0; k < 16; ++k) s += red[k][t];
    size_t node = (size_t)blk * 64 + t;
    if (node < NN) out[node] = s;
  }
}

extern "C" void kernel_launch(void* const* d_in, const int* in_sizes, int n_in,
                              void* d_out, int out_size, void* d_ws, size_t ws_size,
                              hipStream_t stream) {
  const float* x      = (const float*)d_in[0];
  const int*   ei     = (const int*)d_in[1];
  const float* enc_W  = (const float*)d_in[2];
  const float* enc_b  = (const float*)d_in[3];
  const float* msg_W1 = (const float*)d_in[4];
  const float* msg_b1 = (const float*)d_in[5];
  const float* msg_W2 = (const float*)d_in[6];
  const float* msg_b2 = (const float*)d_in[7];
  const float* msg_W3 = (const float*)d_in[8];
  const float* msg_b3 = (const float*)d_in[9];
  const float* gWih   = (const float*)d_in[10];
  const float* gWhh   = (const float*)d_in[11];
  const float* gbih   = (const float*)d_in[12];
  const float* gbhh   = (const float*)d_in[13];
  const float* dW1    = (const float*)d_in[14];
  const float* db1    = (const float*)d_in[15];
  const float* dW2    = (const float*)d_in[16];
  const float* db2    = (const float*)d_in[17];
  const float* dW3    = (const float*)d_in[18];
  const float* db3    = (const float*)d_in[19];
  float* out = (float*)d_out;

  float* ws = (float*)d_ws;
  float* invc = ws;                                    // NP
  float* h    = ws + NP;                               // NP*128 fp32
  float* agg  = h + (size_t)NP * DD;                   // NP*128 fp32
  ushort_t* hbfA = (ushort_t*)(agg + (size_t)NP * DD); // NP*128 ush
  ushort_t* hbfB = hbfA + (size_t)NP * DD;             // NP*128 ush
  ushort_t* Ptb  = hbfB + (size_t)NP * DD;             // NP*256 ush
  ushort_t* Psb  = Ptb + (size_t)NP * HH;              // NP*256 ush
  ushort_t* W2pk = Psb + (size_t)NP * HH;              // 3*65536
  ushort_t* W3pk = W2pk + 3 * 65536;                   // 3*32768
  ushort_t* W1pk = W3pk + 3 * 32768;                   // 3*65536
  ushort_t* Wihpk = W1pk + 3 * 65536;                  // 3*49152
  ushort_t* Whhpk = Wihpk + 3 * 49152;                 // 3*49152
  ushort_t* dW1pk = Whhpk + 3 * 49152;                 // 32768
  ushort_t* dW2pk = dW1pk + 32768;                     // 65536
  int* deg    = (int*)(dW2pk + 65536);                 // NP
  int* cursor = deg + NP;                              // NP
  int* sSrc   = cursor + NP;                           // ET
  int* sTgt   = sSrc + ET;                             // ET

  const int* esrc = ei;
  const int* etgt = ei + NE;

  // edge sort (once)
  hipMemsetAsync(deg, 0, NN * sizeof(int), stream);
  deg_kernel<<<(ET + 255) / 256, 256, 0, stream>>>(etgt, deg);
  scan_kernel<<<1, 1024, 0, stream>>>(deg, cursor, invc);
  scatter_kernel<<<(ET + 255) / 256, 256, 0, stream>>>(esrc, etgt, cursor, sSrc, sTgt);

  encoder_kernel<<<(NN * DD + 255) / 256, 256, 0, stream>>>(x, enc_W, enc_b, h, hbfA);

  // weight packs (once, all layers)
  pack_kernel<<<dim3(32, 3), 256, 0, stream>>>(msg_W2, W2pk, 256, 3, 128, 65536, 65536);
  pack_kernel<<<dim3(16, 3), 256, 0, stream>>>(msg_W3, W3pk, 128, 3, 64, 32768, 32768);
  pack_kernel<<<dim3(32, 3), 256, 0, stream>>>(msg_W1, W1pk, 256, 3, 128, 65536, 65536);
  pack_kernel<<<dim3(24, 3), 256, 0, stream>>>(gWih, Wihpk, 384, 2, 96, 49152, 49152);
  pack_kernel<<<dim3(24, 3), 256, 0, stream>>>(gWhh, Whhpk, 384, 2, 96, 49152, 49152);
  pack_kernel<<<dim3(16, 1), 256, 0, stream>>>(dW1, dW1pk, 256, 2, 64, 0, 0);
  pack_kernel<<<dim3(32, 1), 256, 0, stream>>>(dW2, dW2pk, 256, 3, 128, 0, 0);

  for (int l = 0; l < NLAYERS; ++l) {
    const ushort_t* hin = (l & 1) ? hbfB : hbfA;
    ushort_t* hout = (l & 1) ? hbfA : hbfB;
    proj_kernel<<<NB, 256, 0, stream>>>(hin, W1pk + (size_t)l * 65536, msg_b1 + l * HH, Ptb, Psb);
    hipMemsetAsync(agg, 0, (size_t)NP * DD * sizeof(float), stream);
    edge_kernel<<<EGRID, 256, 0, stream>>>(
        sSrc, sTgt, Ptb, Psb, W2pk + (size_t)l * 65536, msg_b2 + (size_t)l * HH,
        W3pk + (size_t)l * 32768, msg_b3 + (size_t)l * DD, invc, agg);
    gru_kernel<<<NB, 256, 0, stream>>>(
        agg, h, hin, Wihpk + (size_t)l * 49152, Whhpk + (size_t)l * 49152,
        gbih + (size_t)l * 3 * DD, gbhh + (size_t)l * 3 * DD, h, hout);
  }
  dec_kernel<<<NB, 256, 0, stream>>>(hbfB, dW1pk, db1, dW2pk, db2, dW3, db3, out);
}

// Round 10
// 1400.488 us; speedup vs baseline: 1.5786x; 1.0097x over previous
//
#include <hip/hip_runtime.h>
#include <math.h>

#define NN 50000
#define NP 50048      // NN padded to 64; all node arrays sized NP
#define NB 782        // NP/64
#define IN_DIM 16
#define DD 128
#define HH 256
#define NE 800000
#define NLAYERS 3
#define ET (NE + NN)
#define EBLK 13282    // ceil(ET/64)

typedef unsigned short ushort_t;
typedef unsigned int uint_t;
typedef __attribute__((ext_vector_type(8))) short bf16x8;   // 8 bf16 = 4 VGPRs
typedef __attribute__((ext_vector_type(4))) float f32x4;

// tanh(x) = 1 - 2*rcp(exp2(2x*log2e)+1); ±inf exact
__device__ __forceinline__ float fast_tanh(float x) {
  float e = __builtin_amdgcn_exp2f(x * 2.88539008177793f);
  float r = __builtin_amdgcn_rcpf(e + 1.0f);
  return fmaf(-2.0f, r, 1.0f);
}

__device__ __forceinline__ float fast_sigmoid(float x) {
  float e = __builtin_amdgcn_exp2f(x * -1.44269504088896f);
  return __builtin_amdgcn_rcpf(e + 1.0f);
}

__device__ __forceinline__ ushort_t f2bf(float f) {  // RNE fp32->bf16
  uint_t u = __float_as_uint(f);
  u += 0x7FFFu + ((u >> 16) & 1u);
  return (ushort_t)(u >> 16);
}

// pack 2 fp32 -> 2 bf16 (RNE) in one dword; single v_cvt_pk_bf16_f32 on gfx950
__device__ __forceinline__ uint_t pack2bf(float lo, float hi) {
#if __has_builtin(__builtin_amdgcn_cvt_pk_bf16_f32)
  auto v = __builtin_amdgcn_cvt_pk_bf16_f32(lo, hi);
  uint_t r;
  __builtin_memcpy(&r, &v, 4);
  return r;
#else
  return (uint_t)f2bf(lo) | ((uint_t)f2bf(hi) << 16);
#endif
}

__device__ __forceinline__ float bflo(uint_t d) { return __uint_as_float(d << 16); }
__device__ __forceinline__ float bfhi(uint_t d) { return __uint_as_float(d & 0xFFFF0000u); }

// h_bf / agg-frag GLOBAL layout (B-operand frags, K=128), per 64-node group:
//   addr = g64*8192 + ((ct*4 + ks)*64 + q*16 + mr)*8 + j

// ---------------- CSR counting sort (built once, reused 3 layers) ----------------

__global__ void deg_kernel(const int* __restrict__ etgt, int* __restrict__ deg) {
  int e = blockIdx.x * blockDim.x + threadIdx.x;
  if (e >= ET) return;
  int tg = (e < NE) ? etgt[e] : (e - NE);
  atomicAdd(&deg[tg], 1);
}

__global__ __launch_bounds__(1024) void scan_kernel(const int* __restrict__ deg,
                                                    int* __restrict__ cursor,
                                                    float* __restrict__ invc) {
  __shared__ int wsum[16];
  __shared__ int carry_s;
  const int t = threadIdx.x;
  const int lane = t & 63, wid = t >> 6;
  if (t == 0) carry_s = 0;
  __syncthreads();
  for (int base = 0; base < NN; base += 1024) {
    int i = base + t;
    int d = (i < NN) ? deg[i] : 0;
    int v = d;
#pragma unroll
    for (int off = 1; off < 64; off <<= 1) {
      int u = __shfl_up(v, off);
      if (lane >= off) v += u;
    }
    if (lane == 63) wsum[wid] = v;
    __syncthreads();
    int woff = 0;
    for (int k = 0; k < wid; ++k) woff += wsum[k];
    int incl = v + woff;
    int carry = carry_s;
    __syncthreads();
    if (i < NN) {
      cursor[i] = carry + incl - d;
      invc[i] = 1.0f / (float)d;
    }
    if (t == 1023) carry_s = carry + incl;
    __syncthreads();
  }
}

__global__ void scatter_kernel(const int* __restrict__ esrc, const int* __restrict__ etgt,
                               int* __restrict__ cursor, int* __restrict__ sSrc,
                               int* __restrict__ sTgt) {
  int e = blockIdx.x * blockDim.x + threadIdx.x;
  if (e >= ET) return;
  int s, tg;
  if (e < NE) { s = esrc[e]; tg = etgt[e]; }
  else        { s = e - NE;  tg = s; }
  int pos = atomicAdd(&cursor[tg], 1);
  sSrc[pos] = s;
  sTgt[pos] = tg;
}

// ---------------------------------------------------------------------------------

__global__ void encoder_kernel(const float* __restrict__ x, const float* __restrict__ W,
                               const float* __restrict__ b, float* __restrict__ h,
                               ushort_t* __restrict__ hbf) {
  int idx = blockIdx.x * blockDim.x + threadIdx.x;
  if (idx >= NN * DD) return;
  int n = idx >> 7, j = idx & (DD - 1);
  const float* xr = x + n * IN_DIM;
  float acc = b[j];
#pragma unroll
  for (int k = 0; k < IN_DIM; ++k) acc = fmaf(xr[k], W[k * DD + j], acc);
  float v = fast_tanh(acc);
  h[idx] = v;
  const int ct = (n >> 4) & 3, mr = n & 15, ks = j >> 5, q = (j >> 3) & 3, jj = j & 7;
  hbf[(size_t)(n >> 6) * 8192 + (((ct * 4 + ks) * 64) + q * 16 + mr) * 8 + jj] = f2bf(v);
}

// Pack W[K x M] (row-major) into bf16 A-frag order; blockIdx.y = layer.
__global__ void pack_kernel(const float* __restrict__ W, ushort_t* __restrict__ out,
                            int M, int kbsh, int ngrp, int srcStride, int outStride) {
  int tid = blockIdx.x * blockDim.x + threadIdx.x;
  if (tid >= ngrp * 64) return;
  const float* Ws = W + (size_t)blockIdx.y * srcStride;
  ushort_t* os = out + (size_t)blockIdx.y * outStride;
  int lane = tid & 63, g = tid >> 6;
  int ks = g & ((1 << kbsh) - 1);
  int rt = g >> kbsh;
  int m = rt * 16 + (lane & 15);
  int k0 = ks * 32 + ((lane >> 4) << 3);
  uint_t p[4];
#pragma unroll
  for (int d = 0; d < 4; ++d)
    p[d] = pack2bf(Ws[(size_t)(k0 + 2 * d) * M + m], Ws[(size_t)(k0 + 2 * d + 1) * M + m]);
  uint4 o;
  o.x = p[0]; o.y = p[1]; o.z = p[2]; o.w = p[3];
  *(uint4*)(os + (size_t)tid * 8) = o;
}

// Pt/Ps = h @ W1 (+b1 on Pt), MFMA, no LDS. 64 nodes/block, 4 waves. (layer 0 only)
__global__ __launch_bounds__(256) void proj_kernel(
    const ushort_t* __restrict__ hbf, const ushort_t* __restrict__ W1p,
    const float* __restrict__ b1, ushort_t* __restrict__ Ptb, ushort_t* __restrict__ Psb) {
  const int t = threadIdx.x, blk = blockIdx.x;
  const int w = t >> 6, l = t & 63, quad = l >> 4, col = l & 15;
  const ushort_t* hb = hbf + (size_t)blk * 8192;
#pragma unroll
  for (int half = 0; half < 2; ++half) {
    f32x4 acc[4][4];
#pragma unroll
    for (int m = 0; m < 4; ++m)
#pragma unroll
      for (int ct = 0; ct < 4; ++ct) acc[m][ct] = (f32x4){0.f, 0.f, 0.f, 0.f};
#pragma unroll
    for (int ks = 0; ks < 4; ++ks) {
      bf16x8 af[4];
#pragma unroll
      for (int m = 0; m < 4; ++m)
        af[m] = *(const bf16x8*)&W1p[((size_t)((w * 4 + m) * 8 + half * 4 + ks) * 64 + l) * 8];
#pragma unroll
      for (int ct = 0; ct < 4; ++ct) {
        bf16x8 bf = *(const bf16x8*)&hb[((ct * 4 + ks) * 64 + l) * 8];
#pragma unroll
        for (int m = 0; m < 4; ++m)
          acc[m][ct] = __builtin_amdgcn_mfma_f32_16x16x32_bf16(af[m], bf, acc[m][ct], 0, 0, 0);
      }
    }
    ushort_t* out = half ? Psb : Ptb;
#pragma unroll
    for (int m = 0; m < 4; ++m) {
      const int o0 = (w * 4 + m) * 16 + quad * 4;
      f32x4 bb = (f32x4){0.f, 0.f, 0.f, 0.f};
      if (half == 0) bb = *(const f32x4*)(b1 + o0);
#pragma unroll
      for (int ct = 0; ct < 4; ++ct) {
        const size_t node = (size_t)blk * 64 + ct * 16 + col;
        uint2 d;
        d.x = pack2bf(acc[m][ct][0] + bb[0], acc[m][ct][1] + bb[1]);
        d.y = pack2bf(acc[m][ct][2] + bb[2], acc[m][ct][3] + bb[3]);
        *(uint2*)&out[node * HH + o0] = d;
      }
    }
  }
}

// MFMA edge kernel, target-sorted edges, wave-cooperative weights, 4 blocks/CU.
// (R7-proven config; linear block mapping — R9's XCD swizzle was neutral/negative
// because the dominant FETCH component is the unpartitionable random Ps gather.)
__global__ __launch_bounds__(256, 4) void edge_kernel(
    const int* __restrict__ sSrc, const int* __restrict__ sTgt,
    const ushort_t* __restrict__ Ptb, const ushort_t* __restrict__ Psb,
    const ushort_t* __restrict__ W2p, const float* __restrict__ b2,
    const ushort_t* __restrict__ W3p, const float* __restrict__ b3,
    const float* __restrict__ invc, float* __restrict__ agg) {
  __shared__ __align__(16) float vBf[64 * 132];
  __shared__ int sIdx[64];
  __shared__ int tIdx[64];
  ushort_t* vB = (ushort_t*)vBf;
  const int t = threadIdx.x;
  const int e0 = blockIdx.x * 64;
  if (t < 64) {
    int e = e0 + t;
    int s = 0, tg = -1;
    if (e < ET) { s = sSrc[e]; tg = sTgt[e]; }
    sIdx[t] = s;
    tIdx[t] = tg;
  }
  __syncthreads();
  // stage 1: bf16 gather + tanh -> vB (B-frag order)
  {
    const int el = t & 63, c = t >> 6;
    int tg = tIdx[el]; if (tg < 0) tg = 0;
    const int s = sIdx[el];
    const uint4* pt = (const uint4*)(Ptb + (size_t)tg * HH + c * 64);
    const uint4* ps = (const uint4*)(Psb + (size_t)s * HH + c * 64);
    const int ct = el >> 4, mr = el & 15;
#pragma unroll
    for (int g = 0; g < 8; ++g) {
      uint4 av = pt[g];
      uint4 bv = ps[g];
      uint_t ad[4] = {av.x, av.y, av.z, av.w};
      uint_t bd[4] = {bv.x, bv.y, bv.z, bv.w};
      uint_t p[4];
#pragma unroll
      for (int d = 0; d < 4; ++d) {
        float flo = bflo(ad[d]) + bflo(bd[d]);
        float fhi = bfhi(ad[d]) + bfhi(bd[d]);
        p[d] = pack2bf(fast_tanh(flo), fast_tanh(fhi));
      }
      uint4 o;
      o.x = p[0]; o.y = p[1]; o.z = p[2]; o.w = p[3];
      const int ks = c * 2 + (g >> 2);
      const int quad = g & 3;
      *(uint4*)&vB[((ct * 8 + ks) * 64 + quad * 16 + mr) * 8] = o;
    }
  }
  __syncthreads();
  const int w = t >> 6, l = t & 63;
  const int quad = l >> 4, col = l & 15;
  // stage 2: u^T — wave w does A-rows rt = 4w..4w+3, all 4 edge tiles
  f32x4 acc2[4][4];
#pragma unroll
  for (int rp = 0; rp < 4; ++rp)
#pragma unroll
    for (int ct = 0; ct < 4; ++ct) acc2[rp][ct] = (f32x4){0.f, 0.f, 0.f, 0.f};
#pragma unroll
  for (int ks = 0; ks < 8; ++ks) {
    bf16x8 bfrag[4];
#pragma unroll
    for (int ct = 0; ct < 4; ++ct)
      bfrag[ct] = *(const bf16x8*)&vB[((ct * 8 + ks) * 64 + l) * 8];
#pragma unroll
    for (int rp = 0; rp < 4; ++rp) {
      bf16x8 afrag = *(const bf16x8*)&W2p[((size_t)((w * 4 + rp) * 8 + ks) * 64 + l) * 8];
#pragma unroll
      for (int ct = 0; ct < 4; ++ct)
        acc2[rp][ct] = __builtin_amdgcn_mfma_f32_16x16x32_bf16(afrag, bfrag[ct], acc2[rp][ct], 0, 0, 0);
    }
  }
  __syncthreads();
#pragma unroll
  for (int rp = 0; rp < 4; ++rp) {
    f32x4 bb = *(const f32x4*)(b2 + w * 64 + rp * 16 + quad * 4);
#pragma unroll
    for (int ct = 0; ct < 4; ++ct) {
      uint2 d;
      d.x = pack2bf(fast_tanh(acc2[rp][ct][0] + bb[0]), fast_tanh(acc2[rp][ct][1] + bb[1]));
      d.y = pack2bf(fast_tanh(acc2[rp][ct][2] + bb[2]), fast_tanh(acc2[rp][ct][3] + bb[3]));
      const int gidx = (ct * 8 + w * 2 + (rp >> 1)) * 64 + ((rp & 1) * 2 + (quad >> 1)) * 16 + col;
      *(uint2*)&vB[gidx * 8 + (quad & 1) * 4] = d;
    }
  }
  __syncthreads();
  // stage 3: msg^T — wave w does A-rows 2w..2w+1
  f32x4 acc3[2][4];
#pragma unroll
  for (int rp = 0; rp < 2; ++rp)
#pragma unroll
    for (int ct = 0; ct < 4; ++ct) acc3[rp][ct] = (f32x4){0.f, 0.f, 0.f, 0.f};
#pragma unroll
  for (int ks = 0; ks < 8; ++ks) {
    bf16x8 bfrag[4];
#pragma unroll
    for (int ct = 0; ct < 4; ++ct)
      bfrag[ct] = *(const bf16x8*)&vB[((ct * 8 + ks) * 64 + l) * 8];
#pragma unroll
    for (int rp = 0; rp < 2; ++rp) {
      bf16x8 afrag = *(const bf16x8*)&W3p[((size_t)((w * 2 + rp) * 8 + ks) * 64 + l) * 8];
#pragma unroll
      for (int ct = 0; ct < 4; ++ct)
        acc3[rp][ct] = __builtin_amdgcn_mfma_f32_16x16x32_bf16(afrag, bfrag[ct], acc3[rp][ct], 0, 0, 0);
    }
  }
  __syncthreads();
  {
#pragma unroll
    for (int rp = 0; rp < 2; ++rp) {
      const int m0 = w * 32 + rp * 16 + quad * 4;
      f32x4 b3v = *(const f32x4*)(b3 + m0);
#pragma unroll
      for (int ct = 0; ct < 4; ++ct) {
        float4 o4;
        o4.x = acc3[rp][ct][0] + b3v[0];
        o4.y = acc3[rp][ct][1] + b3v[1];
        o4.z = acc3[rp][ct][2] + b3v[2];
        o4.w = acc3[rp][ct][3] + b3v[3];
        *(float4*)(vBf + (ct * 16 + col) * 132 + m0) = o4;
      }
    }
  }
  __syncthreads();
  // segmented reduction with folded 1/deg
  {
    const int j = t & 127;
    const int hb = t >> 7;
    const float* colp = vBf + j;
    int cur = tIdx[hb * 32];
    float a = 0.f;
    for (int e = hb * 32; e < hb * 32 + 32; ++e) {
      int tg = tIdx[e];
      if (tg != cur) {
        if (cur >= 0) atomicAdd(&agg[(size_t)cur * DD + j], a * invc[cur]);
        a = 0.f;
        cur = tg;
      }
      a += colp[e * 132];
    }
    if (cur >= 0) atomicAdd(&agg[(size_t)cur * DD + j], a * invc[cur]);
  }
}

// Fused GRU + next-layer projection. GRU epilogue mirrors the new h_bf frags
// into LDS (hbfL); if doProj, the proj MFMA phase runs in-kernel (B-frags from
// LDS, A-frags/W1 from L2) writing Pt/Ps for the NEXT layer — deletes the
// standalone proj dispatch + the 25.6 MB hbf re-read.
__global__ __launch_bounds__(256, 2) void gru_kernel(
    const float* __restrict__ agg, const float* __restrict__ hg,
    const ushort_t* __restrict__ hbf_in,
    const ushort_t* __restrict__ Wihp, const ushort_t* __restrict__ Whhp,
    const float* __restrict__ bih, const float* __restrict__ bhh,
    float* __restrict__ hg_out, ushort_t* __restrict__ hbf_out,
    int doProj, const ushort_t* __restrict__ W1p, const float* __restrict__ b1,
    ushort_t* __restrict__ Ptb, ushort_t* __restrict__ Psb) {
  __shared__ __align__(16) ushort_t aggF[64 * 128];  // 16 KB, B-frag
  __shared__ __align__(16) float hT[64 * 132];       // 33.8 KB
  __shared__ __align__(16) ushort_t hbfL[64 * 128];  // 16 KB, new-h B-frag mirror
  const int t = threadIdx.x, blk = blockIdx.x;
  const size_t nodeBase = (size_t)blk * 64;
  {
    const int row = t >> 2, c = t & 3;
    const float4* ap = (const float4*)(agg + (nodeBase + row) * DD + c * 32);
    const int ct = row >> 4, mr = row & 15;
#pragma unroll
    for (int g = 0; g < 8; ++g) {
      float4 v = ap[g];
      uint2 d;
      d.x = pack2bf(v.x, v.y);
      d.y = pack2bf(v.z, v.w);
      *(uint2*)&aggF[(((ct * 4 + c) * 64) + (g >> 1) * 16 + mr) * 8 + (g & 1) * 4] = d;
    }
    const float4* hp = (const float4*)(hg + (nodeBase + row) * DD + c * 32);
    float* hrow = hT + row * 132 + c * 32;
#pragma unroll
    for (int g = 0; g < 8; ++g) *(float4*)(hrow + g * 4) = hp[g];
  }
  __syncthreads();
  const int w = t >> 6, l = t & 63, quad = l >> 4, col = l & 15;
  const ushort_t* hbf_blk = hbf_in + nodeBase * DD;
  f32x4 bbr[2], bbz[2], bbin[2], bbhn[2];
#pragma unroll
  for (int m = 0; m < 2; ++m) {
    const int o = (w + 4 * m) * 16 + quad * 4;
    f32x4 i0 = *(const f32x4*)(bih + o),       h0 = *(const f32x4*)(bhh + o);
    f32x4 i1 = *(const f32x4*)(bih + o + 128), h1 = *(const f32x4*)(bhh + o + 128);
    bbr[m] = i0 + h0;
    bbz[m] = i1 + h1;
    bbin[m] = *(const f32x4*)(bih + o + 256);
    bbhn[m] = *(const f32x4*)(bhh + o + 256);
  }
  for (int ct = 0; ct < 4; ++ct) {
    f32x4 acc[8];
#pragma unroll
    for (int i = 0; i < 8; ++i) acc[i] = (f32x4){0.f, 0.f, 0.f, 0.f};
#pragma unroll
    for (int ks = 0; ks < 8; ++ks) {
      bf16x8 bfrag;
      if (ks < 4) bfrag = *(const bf16x8*)&aggF[((ct * 4 + ks) * 64 + l) * 8];
      else        bfrag = *(const bf16x8*)&hbf_blk[((ct * 4 + (ks - 4)) * 64 + l) * 8];
#pragma unroll
      for (int i = 0; i < 6; ++i) {
        const int rt = w + 4 * i;
        bf16x8 afrag = (ks < 4)
            ? *(const bf16x8*)&Wihp[((size_t)(rt * 4 + ks) * 64 + l) * 8]
            : *(const bf16x8*)&Whhp[((size_t)(rt * 4 + ks - 4) * 64 + l) * 8];
        const int tgt = (i < 4) ? i : ((ks < 4) ? i : i + 2);
        acc[tgt] = __builtin_amdgcn_mfma_f32_16x16x32_bf16(afrag, bfrag, acc[tgt], 0, 0, 0);
      }
    }
#pragma unroll
    for (int m = 0; m < 2; ++m) {
      const int or0 = (w + 4 * m) * 16 + quad * 4;
      float* hrow = hT + (ct * 16 + col) * 132 + or0;
      f32x4 hv = *(const f32x4*)hrow;
      f32x4 hnew;
#pragma unroll
      for (int r = 0; r < 4; ++r) {
        float rr = fast_sigmoid(acc[m][r] + bbr[m][r]);
        float zz = fast_sigmoid(acc[2 + m][r] + bbz[m][r]);
        float gin = acc[4 + m][r] + bbin[m][r];
        float ghn = acc[6 + m][r] + bbhn[m][r];
        float nn = fast_tanh(fmaf(rr, ghn, gin));
        hnew[r] = fmaf(zz, hv[r] - nn, nn);
      }
      *(f32x4*)hrow = hnew;
      uint2 d;
      d.x = pack2bf(hnew[0], hnew[1]);
      d.y = pack2bf(hnew[2], hnew[3]);
      const int ksn = 2 * m + (w >> 1);
      const int qn = 2 * (w & 1) + (quad >> 1);
      const int fidx = (((ct * 4 + ksn) * 64) + qn * 16 + col) * 8 + 4 * (quad & 1);
      *(uint2*)&hbf_out[nodeBase * DD + fidx] = d;
      *(uint2*)&hbfL[fidx] = d;  // LDS mirror for fused proj
    }
  }
  __syncthreads();
  {
    const int row = t >> 2, c = t & 3;
    float* dst = hg_out + (nodeBase + row) * DD + c * 32;
    const float* src = hT + row * 132 + c * 32;
#pragma unroll
    for (int g = 0; g < 8; ++g) *(float4*)(dst + g * 4) = *(const float4*)(src + g * 4);
  }
  if (!doProj) return;
  // ---- fused next-layer proj: Pt/Ps = h_new @ W1 (+b1 on Pt) ----
#pragma unroll
  for (int half = 0; half < 2; ++half) {
    f32x4 pacc[4][4];
#pragma unroll
    for (int m = 0; m < 4; ++m)
#pragma unroll
      for (int ct = 0; ct < 4; ++ct) pacc[m][ct] = (f32x4){0.f, 0.f, 0.f, 0.f};
#pragma unroll
    for (int ks = 0; ks < 4; ++ks) {
      bf16x8 af[4];
#pragma unroll
      for (int m = 0; m < 4; ++m)
        af[m] = *(const bf16x8*)&W1p[((size_t)((w * 4 + m) * 8 + half * 4 + ks) * 64 + l) * 8];
#pragma unroll
      for (int ct = 0; ct < 4; ++ct) {
        bf16x8 bf = *(const bf16x8*)&hbfL[((ct * 4 + ks) * 64 + l) * 8];
#pragma unroll
        for (int m = 0; m < 4; ++m)
          pacc[m][ct] = __builtin_amdgcn_mfma_f32_16x16x32_bf16(af[m], bf, pacc[m][ct], 0, 0, 0);
      }
    }
    ushort_t* outp = half ? Psb : Ptb;
#pragma unroll
    for (int m = 0; m < 4; ++m) {
      const int o0 = (w * 4 + m) * 16 + quad * 4;
      f32x4 bb = (f32x4){0.f, 0.f, 0.f, 0.f};
      if (half == 0) bb = *(const f32x4*)(b1 + o0);
#pragma unroll
      for (int ct = 0; ct < 4; ++ct) {
        const size_t node = nodeBase + ct * 16 + col;
        uint2 d;
        d.x = pack2bf(pacc[m][ct][0] + bb[0], pacc[m][ct][1] + bb[1]);
        d.y = pack2bf(pacc[m][ct][2] + bb[2], pacc[m][ct][3] + bb[3]);
        *(uint2*)&outp[node * HH + o0] = d;
      }
    }
  }
}

// Fused decoder
__global__ __launch_bounds__(256) void dec_kernel(
    const ushort_t* __restrict__ hbf, const ushort_t* __restrict__ W1p,
    const float* __restrict__ b1, const ushort_t* __restrict__ W2p,
    const float* __restrict__ b2, const float* __restrict__ w3,
    const float* __restrict__ b3, float* __restrict__ out) {
  __shared__ __align__(16) ushort_t o1F[64 * 256];  // 32 KB
  __shared__ float red[16][64];                     // 4 KB
  const int t = threadIdx.x, blk = blockIdx.x;
  const int w = t >> 6, l = t & 63, quad = l >> 4, col = l & 15;
  const ushort_t* hb = hbf + (size_t)blk * 8192;
  {
    f32x4 a1[4][4];
#pragma unroll
    for (int m = 0; m < 4; ++m)
#pragma unroll
      for (int ct = 0; ct < 4; ++ct) a1[m][ct] = (f32x4){0.f, 0.f, 0.f, 0.f};
#pragma unroll
    for (int ks = 0; ks < 4; ++ks) {
      bf16x8 af[4];
#pragma unroll
      for (int m = 0; m < 4; ++m)
        af[m] = *(const bf16x8*)&W1p[((size_t)((w * 4 + m) * 4 + ks) * 64 + l) * 8];
#pragma unroll
      for (int ct = 0; ct < 4; ++ct) {
        bf16x8 bf = *(const bf16x8*)&hb[((ct * 4 + ks) * 64 + l) * 8];
#pragma unroll
        for (int m = 0; m < 4; ++m)
          a1[m][ct] = __builtin_amdgcn_mfma_f32_16x16x32_bf16(af[m], bf, a1[m][ct], 0, 0, 0);
      }
    }
#pragma unroll
    for (int m = 0; m < 4; ++m) {
      const int o0 = (w * 4 + m) * 16 + quad * 4;
      f32x4 bb = *(const f32x4*)(b1 + o0);
      const int ks1 = 2 * w + (m >> 1);
      const int q1 = 2 * (m & 1) + (quad >> 1);
#pragma unroll
      for (int ct = 0; ct < 4; ++ct) {
        uint2 d;
        d.x = pack2bf(fast_tanh(a1[m][ct][0] + bb[0]), fast_tanh(a1[m][ct][1] + bb[1]));
        d.y = pack2bf(fast_tanh(a1[m][ct][2] + bb[2]), fast_tanh(a1[m][ct][3] + bb[3]));
        *(uint2*)&o1F[((ct * 8 + ks1) * 64 + q1 * 16 + col) * 8 + 4 * (quad & 1)] = d;
      }
    }
  }
  __syncthreads();
  {
    f32x4 a2[4][4];
#pragma unroll
    for (int m = 0; m < 4; ++m)
#pragma unroll
      for (int ct = 0; ct < 4; ++ct) a2[m][ct] = (f32x4){0.f, 0.f, 0.f, 0.f};
#pragma unroll
    for (int ks = 0; ks < 8; ++ks) {
      bf16x8 af[4];
#pragma unroll
      for (int m = 0; m < 4; ++m)
        af[m] = *(const bf16x8*)&W2p[((size_t)((w * 4 + m) * 8 + ks) * 64 + l) * 8];
#pragma unroll
      for (int ct = 0; ct < 4; ++ct) {
        bf16x8 bf = *(const bf16x8*)&o1F[((ct * 8 + ks) * 64 + l) * 8];
#pragma unroll
        for (int m = 0; m < 4; ++m)
          a2[m][ct] = __builtin_amdgcn_mfma_f32_16x16x32_bf16(af[m], bf, a2[m][ct], 0, 0, 0);
      }
    }
    float partial[4] = {0.f, 0.f, 0.f, 0.f};
#pragma unroll
    for (int m = 0; m < 4; ++m) {
      const int o0 = (w * 4 + m) * 16 + quad * 4;
      f32x4 b2v = *(const f32x4*)(b2 + o0);
      f32x4 w3v = *(const f32x4*)(w3 + o0);
#pragma unroll
      for (int ct = 0; ct < 4; ++ct)
#pragma unroll
        for (int r = 0; r < 4; ++r)
          partial[ct] += fast_tanh(a2[m][ct][r] + b2v[r]) * w3v[r];
    }
#pragma unroll
    for (int ct = 0; ct < 4; ++ct) red[w * 4 + quad][ct * 16 + col] = partial[ct];
  }
  __syncthreads();
  if (t < 64) {
    float s = b3[0];
#pragma unroll
    for (int k = 0; k < 16; ++k) s += red[k][t];
    size_t node = (size_t)blk * 64 + t;
    if (node < NN) out[node] = s;
  }
}

extern "C" void kernel_launch(void* const* d_in, const int* in_sizes, int n_in,
                              void* d_out, int out_size, void* d_ws, size_t ws_size,
                              hipStream_t stream) {
  const float* x      = (const float*)d_in[0];
  const int*   ei     = (const int*)d_in[1];
  const float* enc_W  = (const float*)d_in[2];
  const float* enc_b  = (const float*)d_in[3];
  const float* msg_W1 = (const float*)d_in[4];
  const float* msg_b1 = (const float*)d_in[5];
  const float* msg_W2 = (const float*)d_in[6];
  const float* msg_b2 = (const float*)d_in[7];
  const float* msg_W3 = (const float*)d_in[8];
  const float* msg_b3 = (const float*)d_in[9];
  const float* gWih   = (const float*)d_in[10];
  const float* gWhh   = (const float*)d_in[11];
  const float* gbih   = (const float*)d_in[12];
  const float* gbhh   = (const float*)d_in[13];
  const float* dW1    = (const float*)d_in[14];
  const float* db1    = (const float*)d_in[15];
  const float* dW2    = (const float*)d_in[16];
  const float* db2    = (const float*)d_in[17];
  const float* dW3    = (const float*)d_in[18];
  const float* db3    = (const float*)d_in[19];
  float* out = (float*)d_out;

  float* ws = (float*)d_ws;
  float* invc = ws;                                    // NP
  float* h    = ws + NP;                               // NP*128 fp32
  float* agg  = h + (size_t)NP * DD;                   // NP*128 fp32
  ushort_t* hbfA = (ushort_t*)(agg + (size_t)NP * DD); // NP*128 ush
  ushort_t* hbfB = hbfA + (size_t)NP * DD;             // NP*128 ush
  ushort_t* Ptb  = hbfB + (size_t)NP * DD;             // NP*256 ush
  ushort_t* Psb  = Ptb + (size_t)NP * HH;              // NP*256 ush
  ushort_t* W2pk = Psb + (size_t)NP * HH;              // 3*65536
  ushort_t* W3pk = W2pk + 3 * 65536;                   // 3*32768
  ushort_t* W1pk = W3pk + 3 * 32768;                   // 3*65536
  ushort_t* Wihpk = W1pk + 3 * 65536;                  // 3*49152
  ushort_t* Whhpk = Wihpk + 3 * 49152;                 // 3*49152
  ushort_t* dW1pk = Whhpk + 3 * 49152;                 // 32768
  ushort_t* dW2pk = dW1pk + 32768;                     // 65536
  int* deg    = (int*)(dW2pk + 65536);                 // NP
  int* cursor = deg + NP;                              // NP
  int* sSrc   = cursor + NP;                           // ET
  int* sTgt   = sSrc + ET;                             // ET

  const int* esrc = ei;
  const int* etgt = ei + NE;

  // edge sort (once)
  hipMemsetAsync(deg, 0, NN * sizeof(int), stream);
  deg_kernel<<<(ET + 255) / 256, 256, 0, stream>>>(etgt, deg);
  scan_kernel<<<1, 1024, 0, stream>>>(deg, cursor, invc);
  scatter_kernel<<<(ET + 255) / 256, 256, 0, stream>>>(esrc, etgt, cursor, sSrc, sTgt);

  encoder_kernel<<<(NN * DD + 255) / 256, 256, 0, stream>>>(x, enc_W, enc_b, h, hbfA);

  // weight packs (once, all layers)
  pack_kernel<<<dim3(32, 3), 256, 0, stream>>>(msg_W2, W2pk, 256, 3, 128, 65536, 65536);
  pack_kernel<<<dim3(16, 3), 256, 0, stream>>>(msg_W3, W3pk, 128, 3, 64, 32768, 32768);
  pack_kernel<<<dim3(32, 3), 256, 0, stream>>>(msg_W1, W1pk, 256, 3, 128, 65536, 65536);
  pack_kernel<<<dim3(24, 3), 256, 0, stream>>>(gWih, Wihpk, 384, 2, 96, 49152, 49152);
  pack_kernel<<<dim3(24, 3), 256, 0, stream>>>(gWhh, Whhpk, 384, 2, 96, 49152, 49152);
  pack_kernel<<<dim3(16, 1), 256, 0, stream>>>(dW1, dW1pk, 256, 2, 64, 0, 0);
  pack_kernel<<<dim3(32, 1), 256, 0, stream>>>(dW2, dW2pk, 256, 3, 128, 0, 0);

  // layer-0 proj (encoder output); layers 1,2 get Pt/Ps from the fused gru
  proj_kernel<<<NB, 256, 0, stream>>>(hbfA, W1pk, msg_b1, Ptb, Psb);

  for (int l = 0; l < NLAYERS; ++l) {
    const ushort_t* hin = (l & 1) ? hbfB : hbfA;
    ushort_t* hout = (l & 1) ? hbfA : hbfB;
    hipMemsetAsync(agg, 0, (size_t)NP * DD * sizeof(float), stream);
    edge_kernel<<<EBLK, 256, 0, stream>>>(
        sSrc, sTgt, Ptb, Psb, W2pk + (size_t)l * 65536, msg_b2 + (size_t)l * HH,
        W3pk + (size_t)l * 32768, msg_b3 + (size_t)l * DD, invc, agg);
    const int doProj = (l < NLAYERS - 1) ? 1 : 0;
    gru_kernel<<<NB, 256, 0, stream>>>(
        agg, h, hin, Wihpk + (size_t)l * 49152, Whhpk + (size_t)l * 49152,
        gbih + (size_t)l * 3 * DD, gbhh + (size_t)l * 3 * DD, h, hout,
        doProj, W1pk + (size_t)(l + 1) * 65536, msg_b1 + (size_t)(l + 1) * HH, Ptb, Psb);
  }
  dec_kernel<<<NB, 256, 0, stream>>>(hbfB, dW1pk, db1, dW2pk, db2, dW3, db3, out);
}